// Round 1
// baseline (1544.376 us; speedup 1.0000x reference)
//
#include <hip/hip_runtime.h>
#include <hip/hip_bf16.h>

#define N_NODES   50000
#define N_EDGES   800000
#define NF        32
#define DE        64
#define NH        8
#define CT        512     // NH*DE
#define DMLP      512
#define NG        2000
#define NEGS      0.2f

// ---------------- CSR build (shared by both GAT layers) ----------------

__global__ void init_count_k(int* __restrict__ cnt) {
    int i = blockIdx.x * 256 + threadIdx.x;
    if (i < N_NODES) cnt[i] = 1;   // start at 1: the self-loop
}

__global__ void hist_k(const int* __restrict__ ei, int* __restrict__ cnt) {
    int e = blockIdx.x * 256 + threadIdx.x;
    if (e < N_EDGES) atomicAdd(&cnt[ei[N_EDGES + e]], 1);   // row 1 = dst
}

// single-block exclusive scan over 50000 counts (tiny; ~50 chunks of 1024)
__global__ void scan_k(const int* __restrict__ cnt, int* __restrict__ off) {
    __shared__ int buf[1024];
    __shared__ int carry;
    int tid = threadIdx.x;
    if (tid == 0) carry = 0;
    __syncthreads();
    for (int base = 0; base < N_NODES; base += 1024) {
        int v = (base + tid < N_NODES) ? cnt[base + tid] : 0;
        buf[tid] = v;
        __syncthreads();
        for (int d = 1; d < 1024; d <<= 1) {
            int t = (tid >= d) ? buf[tid - d] : 0;
            __syncthreads();
            buf[tid] += t;
            __syncthreads();
        }
        int incl = buf[tid];
        int c = carry;
        int tot = buf[1023];
        __syncthreads();
        if (base + tid < N_NODES) off[base + tid] = c + incl - v;
        if (tid == 0) carry = c + tot;
        __syncthreads();
    }
    if (tid == 0) off[N_NODES] = carry;
}

__global__ void scatter_k(const int* __restrict__ ei, const int* __restrict__ off,
                          int* __restrict__ cur, int* __restrict__ ssrc) {
    int e = blockIdx.x * 256 + threadIdx.x;
    if (e < N_EDGES) {
        int s = ei[e];
        int d = ei[N_EDGES + e];
        int p = off[d] + atomicAdd(&cur[d], 1);
        ssrc[p] = s;
    } else if (e < N_EDGES + N_NODES) {
        int i = e - N_EDGES;                    // self loop
        int p = off[i] + atomicAdd(&cur[i], 1);
        ssrc[p] = i;
    }
}

// ---------------- dense GEMM: Y[nrows,512] = X[nrows,K] @ W[K,512] ----------------
// 8 rows per block, 256 threads, each thread owns channels (tid, tid+256)

template<int K, bool RELU_BIAS>
__global__ void gemm_k(const float* __restrict__ X, const float* __restrict__ W,
                       const float* __restrict__ bias, float* __restrict__ Y, int nrows) {
    __shared__ float xs[8][K];
    int tid = threadIdx.x;
    int row0 = blockIdx.x * 8;
    for (int idx = tid; idx < 8 * K; idx += 256) {
        int r = idx / K, k = idx - r * K;
        int row = row0 + r;
        xs[r][k] = (row < nrows) ? X[(size_t)row * K + k] : 0.f;
    }
    __syncthreads();
    float acc0[8] = {0,0,0,0,0,0,0,0};
    float acc1[8] = {0,0,0,0,0,0,0,0};
    for (int k = 0; k < K; ++k) {
        float w0 = W[(size_t)k * CT + tid];
        float w1 = W[(size_t)k * CT + tid + 256];
        #pragma unroll
        for (int r = 0; r < 8; ++r) {
            acc0[r] = fmaf(xs[r][k], w0, acc0[r]);
            acc1[r] = fmaf(xs[r][k], w1, acc1[r]);
        }
    }
    float b0 = 0.f, b1 = 0.f;
    if (RELU_BIAS) { b0 = bias[tid]; b1 = bias[tid + 256]; }
    #pragma unroll
    for (int r = 0; r < 8; ++r) {
        int row = row0 + r;
        if (row < nrows) {
            float v0 = acc0[r], v1 = acc1[r];
            if (RELU_BIAS) { v0 = fmaxf(v0 + b0, 0.f); v1 = fmaxf(v1 + b1, 0.f); }
            Y[(size_t)row * CT + tid]       = v0;
            Y[(size_t)row * CT + tid + 256] = v1;
        }
    }
}

// ---------------- per-(node,head) attention logits ----------------

__global__ void alpha_k(const float* __restrict__ h, const float* __restrict__ a_src,
                        const float* __restrict__ a_dst, float* __restrict__ as_,
                        float* __restrict__ ad_) {
    __shared__ float sa[CT], sd[CT];
    int tid = threadIdx.x;
    for (int i = tid; i < CT; i += 256) { sa[i] = a_src[i]; sd[i] = a_dst[i]; }
    __syncthreads();
    int gidx = blockIdx.x * 256 + tid;
    if (gidx >= N_NODES * NH) return;
    int n = gidx >> 3, hd = gidx & 7;
    const float4* hp = (const float4*)(h + (size_t)n * CT + hd * DE);
    float s1 = 0.f, s2 = 0.f;
    #pragma unroll
    for (int q = 0; q < DE / 4; ++q) {
        float4 v = hp[q];
        int b = hd * DE + q * 4;
        s1 += v.x * sa[b] + v.y * sa[b + 1] + v.z * sa[b + 2] + v.w * sa[b + 3];
        s2 += v.x * sd[b] + v.y * sd[b + 1] + v.z * sd[b + 2] + v.w * sd[b + 3];
    }
    as_[gidx] = s1;
    ad_[gidx] = s2;
}

// ---------------- GAT aggregation: one block per destination node ----------------
// CONCAT=false: out[i,64] = mean over heads + bias
// CONCAT=true : fused graph pooling atomicAdd into g[batch[i], 512] (+bias)

template<bool CONCAT>
__global__ void agg_k(const float* __restrict__ h, const float* __restrict__ as_,
                      const float* __restrict__ ad_, const int* __restrict__ ssrc,
                      const int* __restrict__ off, const float* __restrict__ bias,
                      float* __restrict__ out, const int* __restrict__ batch,
                      float* __restrict__ g) {
    int i = blockIdx.x;
    int tid = threadIdx.x;
    int beg = off[i], deg = off[i + 1] - beg;

    __shared__ float adv[NH];
    __shared__ float m_sh[NH], is_sh[NH];
    __shared__ float alpha_sh[32][NH];
    __shared__ int   src_sh[32];

    if (tid < NH) adv[tid] = ad_[(size_t)i * NH + tid];
    __syncthreads();

    // Phase A: per-head online (max, sum) over incoming edges; 32 lanes/head
    {
        int hd = tid >> 5, l = tid & 31;
        float adi = adv[hd];
        float m = -1e30f, s = 0.f;
        for (int j = l; j < deg; j += 32) {
            int sj = ssrc[beg + j];
            float e = as_[(size_t)sj * NH + hd] + adi;
            e = e > 0.f ? e : NEGS * e;
            float mo = fmaxf(m, e);
            s = s * __expf(m - mo) + __expf(e - mo);
            m = mo;
        }
        #pragma unroll
        for (int d = 16; d >= 1; d >>= 1) {
            float m2 = __shfl_xor(m, d, 32);
            float s2 = __shfl_xor(s, d, 32);
            float mo = fmaxf(m, m2);
            s = s * __expf(m - mo) + s2 * __expf(m2 - mo);
            m = mo;
        }
        if (l == 0) { m_sh[hd] = m; is_sh[hd] = 1.f / (s + 1e-16f); }
    }
    __syncthreads();

    // Phase B: weighted gather-accumulate, 32-edge chunks
    float acc0 = 0.f, acc1 = 0.f;
    int hd0 = tid >> 6;       // head of channel tid      (0..3)
    int hd1 = hd0 + 4;        // head of channel tid+256  (4..7)
    for (int cb = 0; cb < deg; cb += 32) {
        int clen = min(32, deg - cb);
        int hd = tid >> 5, l = tid & 31;
        if (l < clen) {
            int sj = ssrc[beg + cb + l];
            if (hd == 0) src_sh[l] = sj;
            float e = as_[(size_t)sj * NH + hd] + adv[hd];
            e = e > 0.f ? e : NEGS * e;
            alpha_sh[l][hd] = __expf(e - m_sh[hd]) * is_sh[hd];
        }
        __syncthreads();
        for (int l2 = 0; l2 < clen; ++l2) {
            const float* hr = h + (size_t)src_sh[l2] * CT;
            acc0 = fmaf(alpha_sh[l2][hd0], hr[tid], acc0);
            acc1 = fmaf(alpha_sh[l2][hd1], hr[tid + 256], acc1);
        }
        __syncthreads();
    }

    if (CONCAT) {
        int b = batch[i];
        atomicAdd(&g[(size_t)b * CT + tid],       acc0 + bias[tid]);
        atomicAdd(&g[(size_t)b * CT + tid + 256], acc1 + bias[tid + 256]);
    } else {
        __shared__ float red[CT];
        red[tid] = acc0; red[tid + 256] = acc1;
        __syncthreads();
        if (tid < DE) {
            float s = 0.f;
            #pragma unroll
            for (int hd = 0; hd < NH; ++hd) s += red[hd * DE + tid];
            out[(size_t)i * DE + tid] = s * (1.f / NH) + bias[tid];
        }
    }
}

// ---------------- final MLP projection to 1 ----------------

__global__ void mlp_out_k(const float* __restrict__ gin, const float* __restrict__ w,
                          const float* __restrict__ b, float* __restrict__ out) {
    int row = blockIdx.x * 4 + (threadIdx.x >> 6);
    int lane = threadIdx.x & 63;
    if (row >= NG) return;
    float s = 0.f;
    for (int k = lane; k < DMLP; k += 64) s += gin[(size_t)row * DMLP + k] * w[k];
    #pragma unroll
    for (int d = 32; d >= 1; d >>= 1) s += __shfl_xor(s, d, 64);
    if (lane == 0) out[row] = s + b[0];
}

// ---------------- launch ----------------

extern "C" void kernel_launch(void* const* d_in, const int* in_sizes, int n_in,
                              void* d_out, int out_size, void* d_ws, size_t ws_size,
                              hipStream_t stream) {
    const float* x     = (const float*)d_in[0];
    const int*   ei    = (const int*)d_in[1];
    const int*   batch = (const int*)d_in[2];
    const float* W1    = (const float*)d_in[3];
    const float* asrc1 = (const float*)d_in[4];
    const float* adst1 = (const float*)d_in[5];
    const float* b1    = (const float*)d_in[6];
    const float* W2    = (const float*)d_in[7];
    const float* asrc2 = (const float*)d_in[8];
    const float* adst2 = (const float*)d_in[9];
    const float* b2    = (const float*)d_in[10];
    const float* fcW1  = (const float*)d_in[11];
    const float* fcb1  = (const float*)d_in[12];
    const float* fcW2  = (const float*)d_in[13];
    const float* fcb2  = (const float*)d_in[14];
    const float* fcW3  = (const float*)d_in[15];
    const float* fcb3  = (const float*)d_in[16];

    char* p = (char*)d_ws;
    auto take = [&](size_t bytes) {
        char* r = p;
        p += (bytes + 255) & ~(size_t)255;
        return r;
    };
    float* h    = (float*)take((size_t)N_NODES * CT * 4);   // 102.4 MB (h1 then h2)
    float* hx   = (float*)take((size_t)N_NODES * DE * 4);   // layer1 output
    float* as_  = (float*)take((size_t)N_NODES * NH * 4);
    float* ad_  = (float*)take((size_t)N_NODES * NH * 4);
    int*   ssrc = (int*)take((size_t)(N_EDGES + N_NODES) * 4);
    int*   offv = (int*)take((size_t)(N_NODES + 1) * 4);
    int*   cur  = (int*)take((size_t)N_NODES * 4);
    float* g0   = (float*)take((size_t)NG * DMLP * 4);
    float* g1   = (float*)take((size_t)NG * DMLP * 4);

    // CSR build (once; reused by both layers)
    init_count_k<<<(N_NODES + 255) / 256, 256, 0, stream>>>(cur);
    hist_k<<<(N_EDGES + 255) / 256, 256, 0, stream>>>(ei, cur);
    scan_k<<<1, 1024, 0, stream>>>(cur, offv);
    hipMemsetAsync(cur, 0, (size_t)N_NODES * 4, stream);
    scatter_k<<<(N_EDGES + N_NODES + 255) / 256, 256, 0, stream>>>(ei, offv, cur, ssrc);

    // Layer 1
    gemm_k<NF, false><<<(N_NODES + 7) / 8, 256, 0, stream>>>(x, W1, nullptr, h, N_NODES);
    alpha_k<<<(N_NODES * NH + 255) / 256, 256, 0, stream>>>(h, asrc1, adst1, as_, ad_);
    agg_k<false><<<N_NODES, 256, 0, stream>>>(h, as_, ad_, ssrc, offv, b1, hx, nullptr, nullptr);

    // Layer 2 (h buffer reused; pooling fused into epilogue)
    gemm_k<DE, false><<<(N_NODES + 7) / 8, 256, 0, stream>>>(hx, W2, nullptr, h, N_NODES);
    alpha_k<<<(N_NODES * NH + 255) / 256, 256, 0, stream>>>(h, asrc2, adst2, as_, ad_);
    hipMemsetAsync(g0, 0, (size_t)NG * DMLP * 4, stream);
    agg_k<true><<<N_NODES, 256, 0, stream>>>(h, as_, ad_, ssrc, offv, b2, nullptr, batch, g0);

    // MLP head
    gemm_k<DMLP, true><<<(NG + 7) / 8, 256, 0, stream>>>(g0, fcW1, fcb1, g1, NG);
    gemm_k<DMLP, true><<<(NG + 7) / 8, 256, 0, stream>>>(g1, fcW2, fcb2, g0, NG);
    mlp_out_k<<<(NG + 3) / 4, 256, 0, stream>>>(g0, fcW3, fcb3, (float*)d_out);
}